// Round 1
// 242.129 us; speedup vs baseline: 1.0049x; 1.0049x over previous
//
#include <hip/hip_runtime.h>
#include <math.h>

typedef __attribute__((ext_vector_type(8))) short short8;
typedef __attribute__((ext_vector_type(4))) float floatx4;

__device__ __forceinline__ float bf2f(unsigned short u) {
    union { unsigned int u; float f; } v;
    v.u = ((unsigned int)u) << 16;
    return v.f;
}

__device__ __forceinline__ unsigned short f2bf(float f) {
    union { float f; unsigned int u; } v;
    v.f = f;
    unsigned int r = v.u + 0x7fffu + ((v.u >> 16) & 1u);  // RNE
    return (unsigned short)(r >> 16);
}

__device__ __forceinline__ void gload16_lds(const void* g, void* l) {
    __builtin_amdgcn_global_load_lds(
        (const __attribute__((address_space(1))) unsigned int*)g,
        (__attribute__((address_space(3))) unsigned int*)l, 16, 0, 0);
}

__device__ __forceinline__ ushort4 cvt4(float4 v, float fa) {
    ushort4 o;
    o.x = f2bf(v.x * fa); o.y = f2bf(v.y * fa);
    o.z = f2bf(v.z * fa); o.w = f2bf(v.w * fa);
    return o;
}

// ---------------- fused prep: rows (wave-per-row) | transpose(value) ----------
// blocks [0, nRowBlocks):   grid-stride wave-per-row over M+T rows.
//   row < M:  xb[m] = bf16(x[m]/max(||x_m||,eps)); rowsq[m] = 0
//   row >= M: kf[t] = bf16(key[t]*sigmoid(temp[t])/max(||key_t||,eps))
//   One wave owns a full row (D=1024 f32 = 4x float4 per lane), reduce via
//   __shfl_xor only — no LDS, no __syncthreads, no serial-thread-0 section.
// blocks [nRowBlocks, ...): 64x64 tile transpose VT[c][r] = bf16(val[r][c])
__global__ __launch_bounds__(256) void prep_kernel(
    const float* __restrict__ x, const float* __restrict__ key,
    const float* __restrict__ temp, const float* __restrict__ val,
    unsigned short* __restrict__ xb, unsigned short* __restrict__ kf,
    unsigned short* __restrict__ VT, float* __restrict__ rowsq,
    int M, int T, int D, int Dout, int nRowBlocks) {
    const int bid = blockIdx.x;
    if (bid < nRowBlocks) {
        const int lane = threadIdx.x & 63;
        const int nWaves = nRowBlocks << 2;  // 4 waves per block
        const int totRows = M + T;
        for (int row = (bid << 2) | (int)(threadIdx.x >> 6); row < totRows;
             row += nWaves) {
            const bool isx = row < M;
            const int r = isx ? row : row - M;
            const float4* s4 =
                (const float4*)(isx ? (x + (size_t)r * D) : (key + (size_t)r * D));
            float4 v0 = s4[lane];
            float4 v1 = s4[lane + 64];
            float4 v2 = s4[lane + 128];
            float4 v3 = s4[lane + 192];
            float s = v0.x * v0.x + v0.y * v0.y + v0.z * v0.z + v0.w * v0.w;
            s += v1.x * v1.x + v1.y * v1.y + v1.z * v1.z + v1.w * v1.w;
            s += v2.x * v2.x + v2.y * v2.y + v2.z * v2.z + v2.w * v2.w;
            s += v3.x * v3.x + v3.y * v3.y + v3.z * v3.z + v3.w * v3.w;
#pragma unroll
            for (int o = 32; o > 0; o >>= 1) s += __shfl_xor(s, o, 64);
            float fa = 1.0f / fmaxf(sqrtf(s), 1e-12f);
            if (isx) {
                if (lane == 0) rowsq[r] = 0.0f;
            } else {
                fa = fa / (1.0f + expf(-temp[r]));
            }
            ushort4* dst =
                (ushort4*)(isx ? (xb + (size_t)r * D) : (kf + (size_t)r * D));
            dst[lane] = cvt4(v0, fa);
            dst[lane + 64] = cvt4(v1, fa);
            dst[lane + 128] = cvt4(v2, fa);
            dst[lane + 192] = cvt4(v3, fa);
        }
    } else {
        __shared__ unsigned short tile[64][65];
        const int idx = bid - nRowBlocks;
        const int nCt = Dout >> 6;
        const int c0 = (idx % nCt) * 64;
        const int r0 = (idx / nCt) * 64;
        const int t = threadIdx.x;
        for (int i = t; i < 4096; i += 256) {
            int rr = i >> 6, cc = i & 63;
            tile[rr][cc] = f2bf(val[(size_t)(r0 + rr) * Dout + c0 + cc]);
        }
        __syncthreads();
        for (int i = t; i < 4096; i += 256) {
            int rr = i >> 6, cc = i & 63;
            VT[(size_t)(c0 + rr) * T + r0 + cc] = tile[cc][rr];
        }
    }
}

// ------- 128x128 bf16 MFMA GEMM, C[M,N] = A[M,K] * B[N,K]^T, BK=64 -------------
// grid = (M/128, N/128): linear id = mx + (M/128)*ny -> XCD = mx % 8, so each
// XCD owns M-stripes == k (mod 8); A stripe stays L2-resident across its 8
// N-tile blocks. LDS: two m97-format 32-k subtiles per operand (identity
// staging layout per subtile keeps global_load_lds lane-sequential).
// MODE 0: C(bf16) = acc; rowsq[m] += sum(acc^2)   (GEMM1: sim)
// MODE 1: C(fp32) = acc                           (GEMM2: out)
template <int MODE>
__global__ __launch_bounds__(256) void gemm_bt(const unsigned short* __restrict__ A,
                                               const unsigned short* __restrict__ B,
                                               void* __restrict__ Cv,
                                               float* __restrict__ rowsq,
                                               int M, int N, int K) {
    __shared__ __align__(16) unsigned short As[128 * 64];  // 16 KB: subtile0 | subtile1
    __shared__ __align__(16) unsigned short Bs[128 * 64];
    const int tid = threadIdx.x;
    const int lane = tid & 63;
    const int w = tid >> 6;
    const int m0 = blockIdx.x * 128;   // M on x (fast dim) -> XCD = m-tile % 8
    const int n0 = blockIdx.y * 128;
    const int wm = (w & 1) * 64;
    const int wn = (w >> 1) * 64;
    const int cl = lane & 15;
    const int q = lane >> 4;

    floatx4 acc[4][4];
#pragma unroll
    for (int i = 0; i < 4; i++)
#pragma unroll
        for (int j = 0; j < 4; j++) acc[i][j] = (floatx4){0.f, 0.f, 0.f, 0.f};

    // staging (per 32-k subtile, m97 layout): thread t covers row t>>2,
    // k-offset (t&3)*8; LDS elem offset = chunk*8, lane-sequential per wave
    const int srow = tid >> 2;
    const int skof = (tid & 3) * 8;
    const unsigned short* ga0 = A + (size_t)(m0 + srow) * K + skof;
    const unsigned short* ga1 = A + (size_t)(m0 + srow + 64) * K + skof;
    const unsigned short* gb0 = B + (size_t)(n0 + srow) * K + skof;
    const unsigned short* gb1 = B + (size_t)(n0 + srow + 64) * K + skof;
    unsigned short* la0 = &As[(w * 64) * 8];
    unsigned short* la1 = &As[(256 + w * 64) * 8];
    unsigned short* lb0 = &Bs[(w * 64) * 8];
    unsigned short* lb1 = &Bs[(256 + w * 64) * 8];

    // fragment offsets within a subtile: A[m=lane&15][k=q*8+j], row stride 32
    const int a_off = (wm + cl) * 32 + q * 8;
    const int b_off = (wn + cl) * 32 + q * 8;

    for (int kt = 0; kt < K; kt += 64) {
        __syncthreads();
#pragma unroll
        for (int h = 0; h < 2; h++) {
            const int go = kt + h * 32;
            const int lo = h * 4096;  // elems: 8 KB per subtile
            gload16_lds(ga0 + go, la0 + lo);
            gload16_lds(ga1 + go, la1 + lo);
            gload16_lds(gb0 + go, lb0 + lo);
            gload16_lds(gb1 + go, lb1 + lo);
        }
        __syncthreads();
#pragma unroll
        for (int h = 0; h < 2; h++) {
            const int lo = h * 4096;
            short8 af[4], bfr[4];
#pragma unroll
            for (int mt = 0; mt < 4; mt++)
                af[mt] = *(const short8*)&As[lo + a_off + mt * 16 * 32];
#pragma unroll
            for (int nt = 0; nt < 4; nt++)
                bfr[nt] = *(const short8*)&Bs[lo + b_off + nt * 16 * 32];
#pragma unroll
            for (int mt = 0; mt < 4; mt++)
#pragma unroll
                for (int nt = 0; nt < 4; nt++)
                    acc[mt][nt] = __builtin_amdgcn_mfma_f32_16x16x32_bf16(
                        af[mt], bfr[nt], acc[mt][nt], 0, 0, 0);
        }
    }

    // epilogue — C/D layout: col = lane&15, row = q*4 + reg
#pragma unroll
    for (int mt = 0; mt < 4; mt++) {
#pragma unroll
        for (int r = 0; r < 4; r++) {
            const int m = m0 + wm + mt * 16 + q * 4 + r;
            if (MODE == 0) {
                unsigned short* C = (unsigned short*)Cv;
                float ssq = 0.f;
#pragma unroll
                for (int nt = 0; nt < 4; nt++) {
                    float v = acc[mt][nt][r];
                    ssq += v * v;
                    C[(size_t)m * N + n0 + wn + nt * 16 + cl] = f2bf(v);
                }
#pragma unroll
                for (int o = 1; o < 16; o <<= 1) ssq += __shfl_xor(ssq, o, 64);
                if (cl == 0) atomicAdd(&rowsq[m], ssq);
            } else {
                float* C = (float*)Cv;
#pragma unroll
                for (int nt = 0; nt < 4; nt++)
                    C[(size_t)m * N + n0 + wn + nt * 16 + cl] = acc[mt][nt][r];
            }
        }
    }
}

// ---------- in-place: sim = bf16(gelu_exact(sim * sqrt(T)/sqrt(rowsq[row]))) ---
// Flat grid-stride, 16B (8 bf16) per thread per iteration. rowsq[row] is a
// lane-shared L1 hit (128 consecutive threads share a row).
__global__ __launch_bounds__(256) void gelu_kernel(unsigned short* __restrict__ sim,
                                                   const float* __restrict__ rowsq,
                                                   int nVec, int t8shift,
                                                   float sqrtT) {
    const int stride = gridDim.x * blockDim.x;
    const float kk = 0.70710678118654752f;
    for (int i = blockIdx.x * blockDim.x + threadIdx.x; i < nVec; i += stride) {
        short8 v = *(const short8*)(sim + (size_t)i * 8);
        const int row = i >> t8shift;
        const float scale = sqrtT / fmaxf(sqrtf(rowsq[row]), 1e-30f);
        short8 o;
#pragma unroll
        for (int j = 0; j < 8; j++) {
            float z = bf2f((unsigned short)v[j]) * scale;
            o[j] = (short)f2bf(0.5f * z * (1.0f + erff(z * kk)));
        }
        *(short8*)(sim + (size_t)i * 8) = o;
    }
}

extern "C" void kernel_launch(void* const* d_in, const int* in_sizes, int n_in,
                              void* d_out, int out_size, void* d_ws, size_t ws_size,
                              hipStream_t stream) {
    const float* x    = (const float*)d_in[0];  // [M, D] fp32
    const float* key  = (const float*)d_in[1];  // [T, D] fp32
    const float* val  = (const float*)d_in[2];  // [T, Dout] fp32
    const float* temp = (const float*)d_in[3];  // [T] fp32
    float* out = (float*)d_out;                 // [M, Dout] fp32

    const int T = in_sizes[3];              // 1024
    const int D = in_sizes[1] / T;          // 1024
    const int Dout = in_sizes[2] / T;       // 1024
    const int M = in_sizes[0] / D;          // 16384

    char* ws = (char*)d_ws;
    size_t off = 0;
    unsigned short* xb  = (unsigned short*)(ws + off); off += (size_t)M * D * 2;
    unsigned short* sim = (unsigned short*)(ws + off); off += (size_t)M * T * 2;
    unsigned short* kf  = (unsigned short*)(ws + off); off += (size_t)T * D * 2;
    unsigned short* VT  = (unsigned short*)(ws + off); off += (size_t)Dout * T * 2;
    float* rowsq = (float*)(ws + off); off += (size_t)M * 4;
    (void)ws_size; (void)n_in; (void)out_size;

    const int nTrTiles = (T >> 6) * (Dout >> 6);
    const int nRowBlocks = 1024;  // 4096 waves grid-striding M+T rows
    prep_kernel<<<nRowBlocks + nTrTiles, 256, 0, stream>>>(
        x, key, temp, val, xb, kf, VT, rowsq, M, T, D, Dout, nRowBlocks);
    gemm_bt<0><<<dim3(M / 128, T / 128), 256, 0, stream>>>(xb, kf, sim, rowsq, M, T, D);
    int t8shift = 0;
    {
        int t8 = T >> 3;
        while ((1 << t8shift) < t8) t8shift++;
    }
    gelu_kernel<<<2048, 256, 0, stream>>>(sim, rowsq, M * (T >> 3), t8shift,
                                          sqrtf((float)T));
    gemm_bt<1><<<dim3(M / 128, Dout / 128), 256, 0, stream>>>(sim, VT, out, nullptr,
                                                              M, Dout, T);
}

// Round 2
// 216.855 us; speedup vs baseline: 1.1220x; 1.1165x over previous
//
#include <hip/hip_runtime.h>
#include <math.h>

typedef __attribute__((ext_vector_type(8))) short short8;
typedef __attribute__((ext_vector_type(4))) float floatx4;

__device__ __forceinline__ float bf2f(unsigned short u) {
    union { unsigned int u; float f; } v;
    v.u = ((unsigned int)u) << 16;
    return v.f;
}

__device__ __forceinline__ unsigned short f2bf(float f) {
    union { float f; unsigned int u; } v;
    v.f = f;
    unsigned int r = v.u + 0x7fffu + ((v.u >> 16) & 1u);  // RNE
    return (unsigned short)(r >> 16);
}

__device__ __forceinline__ void gload16_lds(const void* g, void* l) {
    __builtin_amdgcn_global_load_lds(
        (const __attribute__((address_space(1))) unsigned int*)g,
        (__attribute__((address_space(3))) unsigned int*)l, 16, 0, 0);
}

__device__ __forceinline__ ushort4 cvt4(float4 v, float fa) {
    ushort4 o;
    o.x = f2bf(v.x * fa); o.y = f2bf(v.y * fa);
    o.z = f2bf(v.z * fa); o.w = f2bf(v.w * fa);
    return o;
}

// ---------------- fused prep: rows (wave-per-row) | transpose(value) ----------
__global__ __launch_bounds__(256) void prep_kernel(
    const float* __restrict__ x, const float* __restrict__ key,
    const float* __restrict__ temp, const float* __restrict__ val,
    unsigned short* __restrict__ xb, unsigned short* __restrict__ kf,
    unsigned short* __restrict__ VT, float* __restrict__ rowsq,
    int M, int T, int D, int Dout, int nRowBlocks) {
    const int bid = blockIdx.x;
    if (bid < nRowBlocks) {
        const int lane = threadIdx.x & 63;
        const int nWaves = nRowBlocks << 2;  // 4 waves per block
        const int totRows = M + T;
        for (int row = (bid << 2) | (int)(threadIdx.x >> 6); row < totRows;
             row += nWaves) {
            const bool isx = row < M;
            const int r = isx ? row : row - M;
            const float4* s4 =
                (const float4*)(isx ? (x + (size_t)r * D) : (key + (size_t)r * D));
            float4 v0 = s4[lane];
            float4 v1 = s4[lane + 64];
            float4 v2 = s4[lane + 128];
            float4 v3 = s4[lane + 192];
            float s = v0.x * v0.x + v0.y * v0.y + v0.z * v0.z + v0.w * v0.w;
            s += v1.x * v1.x + v1.y * v1.y + v1.z * v1.z + v1.w * v1.w;
            s += v2.x * v2.x + v2.y * v2.y + v2.z * v2.z + v2.w * v2.w;
            s += v3.x * v3.x + v3.y * v3.y + v3.z * v3.z + v3.w * v3.w;
#pragma unroll
            for (int o = 32; o > 0; o >>= 1) s += __shfl_xor(s, o, 64);
            float fa = 1.0f / fmaxf(sqrtf(s), 1e-12f);
            if (isx) {
                if (lane == 0) rowsq[r] = 0.0f;
            } else {
                fa = fa / (1.0f + expf(-temp[r]));
            }
            ushort4* dst =
                (ushort4*)(isx ? (xb + (size_t)r * D) : (kf + (size_t)r * D));
            dst[lane] = cvt4(v0, fa);
            dst[lane + 64] = cvt4(v1, fa);
            dst[lane + 128] = cvt4(v2, fa);
            dst[lane + 192] = cvt4(v3, fa);
        }
    } else {
        __shared__ unsigned short tile[64][65];
        const int idx = bid - nRowBlocks;
        const int nCt = Dout >> 6;
        const int c0 = (idx % nCt) * 64;
        const int r0 = (idx / nCt) * 64;
        const int t = threadIdx.x;
        for (int i = t; i < 4096; i += 256) {
            int rr = i >> 6, cc = i & 63;
            tile[rr][cc] = f2bf(val[(size_t)(r0 + rr) * Dout + c0 + cc]);
        }
        __syncthreads();
        for (int i = t; i < 4096; i += 256) {
            int rr = i >> 6, cc = i & 63;
            VT[(size_t)(c0 + rr) * T + r0 + cc] = tile[cc][rr];
        }
    }
}

// ===== 256x256 bf16 MFMA GEMM, 8-phase-style counted-vmcnt pipeline ==========
// C[M,N] = A[M,K] * B[N,K]^T.  8 waves (2M x 4N), per-wave 128x64 output.
// BK=32 K-tiles, 4-slot LDS ring (4 x (16KB A + 16KB B) = 128 KB).
// LDS layout: subtiled [row/16][16][32] bf16, st_16x32 swizzle
//   (byte ^= 32 when row&8) applied to BOTH staging source lanes and ds_read.
// Schedule per tile (2 phases of 16 MFMA): stage tile t+3 (slot freed at
// tile t-1's last barrier), vmcnt(8) once per tile -> tile t+1 landed.
// Raw s_barrier (no vmcnt drain). Liveness: a wave passes the post-MFMA
// barrier only after its lgkm-waited ds_reads complete, and stage gloads are
// issued only after that barrier -> no LDS write/read race.
// MODE 0: C(bf16) = acc; rowsq[m] += sum(acc^2)   (GEMM1: sim)
// MODE 1: C(fp32) = acc                           (GEMM2: out)
template <int MODE>
__global__ __launch_bounds__(512, 2) void gemm256(
    const unsigned short* __restrict__ A, const unsigned short* __restrict__ B,
    void* __restrict__ Cv, float* __restrict__ rowsq, int M, int N, int K) {
    __shared__ __align__(16) char smem[131072];  // 4 slots x (A 16KB | B 16KB)
    const int tid = threadIdx.x;
    const int lane = tid & 63;
    const int w = tid >> 6;       // wave 0..7
    const int wr = w >> 2;        // 0..1  (M)
    const int wc = w & 3;         // 0..3  (N)
    const int m0 = blockIdx.x * 256;
    const int n0 = blockIdx.y * 256;
    const int q = lane >> 4;
    const int cl = lane & 15;

    // ---- staging addressing (pre-swizzled global source, rule #21) ----
    // lane covers subtile row (lane>>2), 16B chunk ((lane&3) ^ ((lane&32)>>4))
    const int srow = lane >> 2;
    const int sch = (lane & 3) ^ ((lane & 32) >> 4);
    const unsigned short* gA0 = A + (size_t)(m0 + w * 16 + srow) * K + sch * 8;
    const unsigned short* gA1 = gA0 + (size_t)128 * K;
    const unsigned short* gB0 = B + (size_t)(n0 + w * 16 + srow) * K + sch * 8;
    const unsigned short* gB1 = gB0 + (size_t)128 * K;
    // wave-uniform LDS dst: subtile (h*8 + w) of the slot (HW appends lane*16)

    // ---- ds_read per-lane base: logical (row=lane&15)*64 + q*16, swizzled --
    const int LB = (((lane & 15) * 64 + q * 16) ^ ((lane & 8) << 2));

    floatx4 acc[8][4];
#pragma unroll
    for (int i = 0; i < 8; i++)
#pragma unroll
        for (int j = 0; j < 4; j++) acc[i][j] = (floatx4){0.f, 0.f, 0.f, 0.f};

    const int NT = K >> 5;  // BK=32 tiles

    auto stage_h = [&](int t, int h) {
        char* base = smem + (size_t)(t & 3) * 32768 + (h * 8 + w) * 1024;
        const size_t ro = (size_t)h * 128 * K;
        const size_t ko = (size_t)t * 32;
        gload16_lds(gA0 + ro + ko, base);
        gload16_lds(gB0 + ro + ko, base + 16384);
    };
    (void)gA1; (void)gB1;

    // prologue: stage tiles 0,1,2 (12 gloads) -> wait tile 0 (8 may fly)
    stage_h(0, 0); stage_h(0, 1);
    stage_h(1, 0); stage_h(1, 1);
    stage_h(2, 0); stage_h(2, 1);
    asm volatile("s_waitcnt vmcnt(8)" ::: "memory");
    __builtin_amdgcn_s_barrier();

    for (int tt = 0; tt < NT; ++tt) {
        const char* sA = smem + (size_t)(tt & 3) * 32768;
        const char* sB = sA + 16384;
        const bool st = (tt + 3) < NT;
        short8 bf[4], af[4];
        // ---------------- phase 0: B(all nt) + A(mt 0..3) ----------------
#pragma unroll
        for (int nt = 0; nt < 4; ++nt)
            bf[nt] = *(const short8*)(sB + (wc * 4 + nt) * 1024 + LB);
#pragma unroll
        for (int mt = 0; mt < 4; ++mt)
            af[mt] = *(const short8*)(sA + (wr * 8 + mt) * 1024 + LB);
        if (st) stage_h(tt + 3, 0);
        __builtin_amdgcn_s_barrier();
        asm volatile("s_waitcnt lgkmcnt(0)" ::: "memory");
        __builtin_amdgcn_s_setprio(1);
#pragma unroll
        for (int mt = 0; mt < 4; ++mt)
#pragma unroll
            for (int nt = 0; nt < 4; ++nt)
                acc[mt][nt] = __builtin_amdgcn_mfma_f32_16x16x32_bf16(
                    af[mt], bf[nt], acc[mt][nt], 0, 0, 0);
        __builtin_amdgcn_s_setprio(0);
        __builtin_amdgcn_s_barrier();
        __builtin_amdgcn_sched_barrier(0);
        // ---------------- phase 1: A(mt 4..7) ----------------------------
#pragma unroll
        for (int mt = 0; mt < 4; ++mt)
            af[mt] = *(const short8*)(sA + (wr * 8 + 4 + mt) * 1024 + LB);
        if (st) stage_h(tt + 3, 1);
        if (tt < NT - 3) {
            asm volatile("s_waitcnt vmcnt(8)" ::: "memory");
        } else if (tt == NT - 3) {
            asm volatile("s_waitcnt vmcnt(4)" ::: "memory");
        } else if (tt == NT - 2) {
            asm volatile("s_waitcnt vmcnt(0)" ::: "memory");
        }
        __builtin_amdgcn_s_barrier();
        asm volatile("s_waitcnt lgkmcnt(0)" ::: "memory");
        __builtin_amdgcn_s_setprio(1);
#pragma unroll
        for (int mt = 0; mt < 4; ++mt)
#pragma unroll
            for (int nt = 0; nt < 4; ++nt)
                acc[4 + mt][nt] = __builtin_amdgcn_mfma_f32_16x16x32_bf16(
                    af[mt], bf[nt], acc[4 + mt][nt], 0, 0, 0);
        __builtin_amdgcn_s_setprio(0);
        __builtin_amdgcn_s_barrier();
        __builtin_amdgcn_sched_barrier(0);
    }

    // epilogue — C/D layout: col = lane&15, row = q*4 + reg
#pragma unroll
    for (int mt = 0; mt < 8; ++mt) {
#pragma unroll
        for (int r = 0; r < 4; ++r) {
            const int m = m0 + wr * 128 + mt * 16 + q * 4 + r;
            if (MODE == 0) {
                unsigned short* C = (unsigned short*)Cv;
                float ssq = 0.f;
#pragma unroll
                for (int nt = 0; nt < 4; ++nt) {
                    float v = acc[mt][nt][r];
                    ssq += v * v;
                    C[(size_t)m * N + n0 + wc * 64 + nt * 16 + cl] = f2bf(v);
                }
#pragma unroll
                for (int o = 1; o < 16; o <<= 1) ssq += __shfl_xor(ssq, o, 64);
                if (cl == 0) atomicAdd(&rowsq[m], ssq);
            } else {
                float* C = (float*)Cv;
#pragma unroll
                for (int nt = 0; nt < 4; ++nt)
                    C[(size_t)m * N + n0 + wc * 64 + nt * 16 + cl] =
                        acc[mt][nt][r];
            }
        }
    }
}

// ---------- in-place: sim = bf16(gelu_exact(sim * sqrt(T)/sqrt(rowsq[row]))) ---
__global__ __launch_bounds__(256) void gelu_kernel(unsigned short* __restrict__ sim,
                                                   const float* __restrict__ rowsq,
                                                   int nVec, int t8shift,
                                                   float sqrtT) {
    const int stride = gridDim.x * blockDim.x;
    const float kk = 0.70710678118654752f;
    for (int i = blockIdx.x * blockDim.x + threadIdx.x; i < nVec; i += stride) {
        short8 v = *(const short8*)(sim + (size_t)i * 8);
        const int row = i >> t8shift;
        const float scale = sqrtT / fmaxf(sqrtf(rowsq[row]), 1e-30f);
        short8 o;
#pragma unroll
        for (int j = 0; j < 8; j++) {
            float z = bf2f((unsigned short)v[j]) * scale;
            o[j] = (short)f2bf(0.5f * z * (1.0f + erff(z * kk)));
        }
        *(short8*)(sim + (size_t)i * 8) = o;
    }
}

extern "C" void kernel_launch(void* const* d_in, const int* in_sizes, int n_in,
                              void* d_out, int out_size, void* d_ws, size_t ws_size,
                              hipStream_t stream) {
    const float* x    = (const float*)d_in[0];  // [M, D] fp32
    const float* key  = (const float*)d_in[1];  // [T, D] fp32
    const float* val  = (const float*)d_in[2];  // [T, Dout] fp32
    const float* temp = (const float*)d_in[3];  // [T] fp32
    float* out = (float*)d_out;                 // [M, Dout] fp32

    const int T = in_sizes[3];              // 1024
    const int D = in_sizes[1] / T;          // 1024
    const int Dout = in_sizes[2] / T;       // 1024
    const int M = in_sizes[0] / D;          // 16384

    char* ws = (char*)d_ws;
    size_t off = 0;
    unsigned short* xb  = (unsigned short*)(ws + off); off += (size_t)M * D * 2;
    unsigned short* sim = (unsigned short*)(ws + off); off += (size_t)M * T * 2;
    unsigned short* kf  = (unsigned short*)(ws + off); off += (size_t)T * D * 2;
    unsigned short* VT  = (unsigned short*)(ws + off); off += (size_t)Dout * T * 2;
    float* rowsq = (float*)(ws + off); off += (size_t)M * 4;
    (void)ws_size; (void)n_in; (void)out_size;

    const int nTrTiles = (T >> 6) * (Dout >> 6);
    const int nRowBlocks = 1024;  // 4096 waves grid-striding M+T rows
    prep_kernel<<<nRowBlocks + nTrTiles, 256, 0, stream>>>(
        x, key, temp, val, xb, kf, VT, rowsq, M, T, D, Dout, nRowBlocks);
    gemm256<0><<<dim3(M / 256, T / 256), 512, 0, stream>>>(xb, kf, sim, rowsq,
                                                           M, T, D);
    int t8shift = 0;
    {
        int t8 = T >> 3;
        while ((1 << t8shift) < t8) t8shift++;
    }
    gelu_kernel<<<2048, 256, 0, stream>>>(sim, rowsq, M * (T >> 3), t8shift,
                                          sqrtf((float)T));
    gemm256<1><<<dim3(M / 256, Dout / 256), 512, 0, stream>>>(sim, VT, out,
                                                              nullptr, M, Dout, T);
}